// Round 1
// baseline (756.409 us; speedup 1.0000x reference)
//
#include <hip/hip_runtime.h>
#include <math.h>

#define NB 4
#define NN 4096
#define NF 15
#define NA 24
#define NAFN 14
#define NHID 10
#define KSEL 204
#define QKSCALE 0.31622776601683794f

// workspace layout in floats
#define WS_Q 0
#define WS_KT (NB * NN * NHID)       // 163840
#define WS_V (2 * NB * NN * NHID)    // 327680
#define WS_LG (3 * NB * NN * NHID)   // 491520  (+ NB*NN*2 = 32768)

#define SEQ_PER_BLOCK 16

__global__ __launch_bounds__(256) void featqkv_kernel(
    const float* __restrict__ x,
    const float* __restrict__ w2, const float* __restrict__ b2,
    const float* __restrict__ w3, const float* __restrict__ b3,
    const float* __restrict__ w4, const float* __restrict__ b4,
    const float* __restrict__ w5, const float* __restrict__ b5,
    const float* __restrict__ w6, const float* __restrict__ b6,
    const float* __restrict__ w7, const float* __restrict__ b7,
    const float* __restrict__ wq, const float* __restrict__ bq,
    const float* __restrict__ wk, const float* __restrict__ bk,
    const float* __restrict__ wv, const float* __restrict__ bv,
    float* __restrict__ q_out, float* __restrict__ kT_out, float* __restrict__ v_out)
{
    __shared__ float xs[SEQ_PER_BLOCK * 360];
    __shared__ float wconv[840];
    __shared__ float bconv[14];
    __shared__ float wqkv[420];
    __shared__ float bqkv[30];
    __shared__ float feats[SEQ_PER_BLOCK * 14];

    const int t = threadIdx.x;
    const int g0 = blockIdx.x * SEQ_PER_BLOCK;

    // stage x tile (coalesced)
    const float* xg = x + (size_t)g0 * 360;
    for (int i = t; i < SEQ_PER_BLOCK * 360; i += 256) xs[i] = xg[i];
    // stage conv weights: offsets 0,90,225,405,555,735
    for (int i = t; i < 90; i += 256) wconv[i] = w2[i];
    for (int i = t; i < 135; i += 256) wconv[90 + i] = w3[i];
    for (int i = t; i < 180; i += 256) wconv[225 + i] = w4[i];
    for (int i = t; i < 150; i += 256) wconv[405 + i] = w5[i];
    for (int i = t; i < 180; i += 256) wconv[555 + i] = w6[i];
    for (int i = t; i < 105; i += 256) wconv[735 + i] = w7[i];
    if (t < 3) bconv[t] = b2[t];
    else if (t < 6) bconv[t] = b3[t - 3];
    else if (t < 9) bconv[t] = b4[t - 6];
    else if (t < 11) bconv[t] = b5[t - 9];
    else if (t < 13) bconv[t] = b6[t - 11];
    else if (t == 13) bconv[t] = b7[0];
    for (int i = t; i < 140; i += 256) wqkv[i] = wq[i];
    for (int i = t; i < 140; i += 256) wqkv[140 + i] = wk[i];
    for (int i = t; i < 140; i += 256) wqkv[280 + i] = wv[i];
    if (t < 10) bqkv[t] = bq[t];
    else if (t < 20) bqkv[t] = bk[t - 10];
    else if (t < 30) bqkv[t] = bv[t - 20];
    __syncthreads();

    const int seq = t >> 4;
    const int wkr = t & 15;

    if (wkr < 14) {
        const int ch = wkr;
        int h, fi, woff;
        if (ch < 3)       { h = 2; fi = ch;      woff = 0   + fi * 30; }
        else if (ch < 6)  { h = 3; fi = ch - 3;  woff = 90  + fi * 45; }
        else if (ch < 9)  { h = 4; fi = ch - 6;  woff = 225 + fi * 60; }
        else if (ch < 11) { h = 5; fi = ch - 9;  woff = 405 + fi * 75; }
        else if (ch < 13) { h = 6; fi = ch - 11; woff = 555 + fi * 90; }
        else              { h = 7; fi = 0;       woff = 735; }
        const int T = 24 - h + 1;

        float acc[23];
#pragma unroll
        for (int i2 = 0; i2 < 23; i2++) acc[i2] = 0.f;
        const float* xrow = &xs[seq * 360];
        for (int c = 0; c < 15; c++) {
            float xr[24];
#pragma unroll
            for (int u = 0; u < 24; u++) xr[u] = xrow[c * 24 + u];
#pragma unroll
            for (int j = 0; j < 7; j++) {
                if (j < h) {
                    float wv_ = wconv[woff + c * h + j];
#pragma unroll
                    for (int tt = 0; tt < 23; tt++) {
                        if (tt < T) acc[tt] = fmaf(xr[tt + j], wv_, acc[tt]);
                    }
                }
            }
        }
        float m = -1e30f;
#pragma unroll
        for (int tt = 0; tt < 23; tt++) {
            if (tt < T) m = fmaxf(m, acc[tt]);
        }
        feats[seq * 14 + ch] = fmaxf(m + bconv[ch], 0.f);
    }
    __syncthreads();

    // QKV: 30 outputs per sequence across 16 workers
    const int g = g0 + seq;
    const int b_ = g >> 12;
    const int n_ = g & 4095;
    for (int o = wkr; o < 30; o += 16) {
        const int type = o / 10;
        const int comp = o % 10;
        const float* wrow = &wqkv[type * 140 + comp * 14];
        const float* frow = &feats[seq * 14];
        float a = bqkv[type * 10 + comp];
#pragma unroll
        for (int ii = 0; ii < 14; ii++) a = fmaf(frow[ii], wrow[ii], a);
        if (type == 0) q_out[(size_t)g * 10 + comp] = a;
        else if (type == 1) kT_out[((size_t)b_ * 10 + comp) * NN + n_] = a;
        else v_out[(size_t)g * 10 + comp] = a;
    }
}

__device__ __forceinline__ unsigned long long make_key(float f, int j) {
    unsigned int u = __float_as_uint(f);
    u = (u & 0x80000000u) ? ~u : (u | 0x80000000u);  // monotonic ascending map
    return (((unsigned long long)u) << 16) | (unsigned long long)(4095 - j);
}

__global__ __launch_bounds__(256) void attn_kernel(
    const float* __restrict__ qbuf, const float* __restrict__ kTbuf,
    const float* __restrict__ vbuf,
    const float* __restrict__ w_attn, const float* __restrict__ b_attn,
    const float* __restrict__ w_mil, const float* __restrict__ b_mil,
    float* __restrict__ out_probs, float* __restrict__ logits)
{
    __shared__ float sArr[2][4096];
    __shared__ unsigned int hist[256];
    __shared__ unsigned long long keys[256];
    __shared__ float red[256];
    __shared__ float qsh[20];
    __shared__ float attn_out[14];
    __shared__ unsigned long long prefix_sh;
    __shared__ unsigned int kept_sh;
    __shared__ unsigned int cnt;
    __shared__ float mval_sh;

    const int t = threadIdx.x;
    const int r0 = blockIdx.x * 2;           // two rows per block, same batch
    const int b_ = r0 >> 12;

    // ---- P1: scores for both rows ----
    if (t < 20) qsh[t] = qbuf[(size_t)r0 * 10 + t];
    __syncthreads();
    float q0[10], q1[10];
#pragma unroll
    for (int c = 0; c < 10; c++) { q0[c] = qsh[c]; q1[c] = qsh[10 + c]; }
    const float* kTb = kTbuf + (size_t)b_ * 10 * NN;
    for (int j = t; j < NN; j += 256) {
        float a0 = 0.f, a1 = 0.f;
#pragma unroll
        for (int c = 0; c < 10; c++) {
            float kv = kTb[c * NN + j];
            a0 = fmaf(q0[c], kv, a0);
            a1 = fmaf(q1[c], kv, a1);
        }
        sArr[0][j] = a0;
        sArr[1][j] = a1;
    }
    __syncthreads();

    for (int r = 0; r < 2; r++) {
        float* s = sArr[r];
        const size_t row = (size_t)(r0 + r);

        // ---- P2: radix select the 204th-largest composite key ----
        unsigned long long prefix = 0ULL;
        unsigned int kept = KSEL;
        for (int pass = 0; pass < 6; pass++) {
            const int shift = 40 - pass * 8;
            hist[t] = 0u;
            __syncthreads();
            for (int j = t; j < NN; j += 256) {
                unsigned long long key = make_key(s[j], j);
                if ((key >> (shift + 8)) == (prefix >> (shift + 8))) {
                    unsigned int bin = (unsigned int)(key >> shift) & 255u;
                    atomicAdd(&hist[bin], 1u);
                }
            }
            __syncthreads();
            // in-place suffix scan (Hillis-Steele)
            for (int off = 1; off < 256; off <<= 1) {
                unsigned int v0 = hist[t];
                unsigned int v1 = (t + off < 256) ? hist[t + off] : 0u;
                __syncthreads();
                hist[t] = v0 + v1;
                __syncthreads();
            }
            unsigned int suft = hist[t];
            unsigned int sufn = (t < 255) ? hist[t + 1] : 0u;
            if (suft >= kept && sufn < kept) {
                prefix_sh = prefix | (((unsigned long long)t) << shift);
                kept_sh = kept - sufn;
            }
            __syncthreads();
            prefix = prefix_sh;
            kept = kept_sh;
            __syncthreads();
        }
        // prefix == exact 204th-largest key (all keys distinct)

        // ---- P3: compact survivors ----
        keys[t] = 0ULL;
        if (t == 0) cnt = 0u;
        __syncthreads();
        for (int j = t; j < NN; j += 256) {
            unsigned long long key = make_key(s[j], j);
            if (key >= prefix) {
                unsigned int p = atomicAdd(&cnt, 1u);
                keys[p] = key;
            }
        }
        __syncthreads();

        // ---- P4: bitonic sort 256 keys, descending ----
        for (int k2 = 2; k2 <= 256; k2 <<= 1) {
            for (int j2 = k2 >> 1; j2 > 0; j2 >>= 1) {
                int ixj = t ^ j2;
                if (ixj > t) {
                    unsigned long long a = keys[t];
                    unsigned long long bk = keys[ixj];
                    bool up = (t & k2) != 0;
                    bool sw = up ? (a > bk) : (a < bk);
                    if (sw) { keys[t] = bk; keys[ixj] = a; }
                }
                __syncthreads();
            }
        }

        // ---- P5: softmax over selected (sorted) scores ----
        if (t == 0) {
            int j0 = 4095 - (int)(keys[0] & 0xFFFFu);
            mval_sh = s[j0] * QKSCALE;
        }
        __syncthreads();
        const float mv = mval_sh;
        int jj = 0;
        float pv = 0.f;
        if (t < KSEL) {
            jj = 4095 - (int)(keys[t] & 0xFFFFu);
            pv = expf(s[jj] * QKSCALE - mv);
        }
        red[t] = pv;
        __syncthreads();
        for (int off = 128; off > 0; off >>= 1) {
            if (t < off) red[t] += red[t + off];
            __syncthreads();
        }
        const float pn = pv * (1.f / red[0]);
        if (t < KSEL) out_probs[row * KSEL + t] = pn;

        // ---- P6: ctx = sum_k p_k * v[idx_k]  (reuse s as scratch) ----
        // all reads of s finished before the reduction barriers above
        float* scratch = s;
        if (t < KSEL) {
            const float* vr = vbuf + ((size_t)b_ * NN + (size_t)jj) * 10;
#pragma unroll
            for (int d = 0; d < 10; d++) scratch[d * 256 + t] = pn * vr[d];
        } else {
#pragma unroll
            for (int d = 0; d < 10; d++) scratch[d * 256 + t] = 0.f;
        }
        __syncthreads();
        for (int off = 128; off > 0; off >>= 1) {
            if (t < off) {
#pragma unroll
                for (int d = 0; d < 10; d++)
                    scratch[d * 256 + t] += scratch[d * 256 + t + off];
            }
            __syncthreads();
        }

        // ---- P7: attn projection + mil logits ----
        if (t < 14) {
            float a = b_attn[t];
#pragma unroll
            for (int d = 0; d < 10; d++) a = fmaf(scratch[d * 256], w_attn[t * 10 + d], a);
            attn_out[t] = a;
        }
        __syncthreads();
        if (t < 2) {
            float lg = b_mil[t];
#pragma unroll
            for (int ii = 0; ii < 14; ii++) lg = fmaf(attn_out[ii], w_mil[t * 14 + ii], lg);
            logits[row * 2 + t] = lg;
        }
        __syncthreads();  // protect shared buffers before next row
    }
}

__global__ __launch_bounds__(256) void pool_kernel(
    const float* __restrict__ logits, float* __restrict__ out)
{
    __shared__ float red[256];
    const int t = threadIdx.x;
    const int bc = blockIdx.x;       // 0..7: b = bc>>1, c = bc&1
    const int b_ = bc >> 1;
    const int c_ = bc & 1;
    float a = 0.f;
    for (int n2 = t; n2 < NN; n2 += 256)
        a += logits[((size_t)b_ * NN + n2) * 2 + c_];
    red[t] = a;
    __syncthreads();
    for (int off = 128; off > 0; off >>= 1) {
        if (t < off) red[t] += red[t + off];
        __syncthreads();
    }
    if (t == 0) out[bc] = red[0] * (1.f / 4096.f);
}

extern "C" void kernel_launch(void* const* d_in, const int* in_sizes, int n_in,
                              void* d_out, int out_size, void* d_ws, size_t ws_size,
                              hipStream_t stream) {
    const float* x  = (const float*)d_in[0];
    const float* w2 = (const float*)d_in[1];  const float* b2 = (const float*)d_in[2];
    const float* w3 = (const float*)d_in[3];  const float* b3 = (const float*)d_in[4];
    const float* w4 = (const float*)d_in[5];  const float* b4 = (const float*)d_in[6];
    const float* w5 = (const float*)d_in[7];  const float* b5 = (const float*)d_in[8];
    const float* w6 = (const float*)d_in[9];  const float* b6 = (const float*)d_in[10];
    const float* w7 = (const float*)d_in[11]; const float* b7 = (const float*)d_in[12];
    const float* wq = (const float*)d_in[13]; const float* bq = (const float*)d_in[14];
    const float* wk = (const float*)d_in[15]; const float* bk = (const float*)d_in[16];
    const float* wv = (const float*)d_in[17]; const float* bv = (const float*)d_in[18];
    const float* wat = (const float*)d_in[19]; const float* bat = (const float*)d_in[20];
    const float* wm = (const float*)d_in[21];  const float* bm = (const float*)d_in[22];

    float* ws = (float*)d_ws;
    float* qb = ws + WS_Q;
    float* kT = ws + WS_KT;
    float* vb = ws + WS_V;
    float* lg = ws + WS_LG;
    float* out = (float*)d_out;

    hipLaunchKernelGGL(featqkv_kernel, dim3(NB * NN / SEQ_PER_BLOCK), dim3(256), 0, stream,
                       x, w2, b2, w3, b3, w4, b4, w5, b5, w6, b6, w7, b7,
                       wq, bq, wk, bk, wv, bv, qb, kT, vb);
    hipLaunchKernelGGL(attn_kernel, dim3(NB * NN / 2), dim3(256), 0, stream,
                       qb, kT, vb, wat, bat, wm, bm, out + 8, lg);
    hipLaunchKernelGGL(pool_kernel, dim3(8), dim3(256), 0, stream, lg, out);
}